// Round 10
// baseline (113.562 us; speedup 1.0000x reference)
//
#include <hip/hip_runtime.h>
#include <hip/hip_bf16.h>
#include <math.h>

// Problem constants
#define C_IN   256
#define C_QK   128
#define NH     8
#define H_     96
#define W_     96
#define NQ     (H_*W_)          // 9216
#define HD     48
#define WD     48
#define NK     (HD*WD)          // 2304
#define DQ     16
#define DV     32
#define NQC    (NQ/32)          // 288 query chunks
#define NKC    (NK/32)          // 72 key chunks
#define KQRT   (NKC/4)          // 18 key chunks per wave
#define KSTEPS (C_IN/16)        // 16 MFMA k-steps per GEMM tile
#define QS     0.3606737602222409f   // 0.25 * log2(e)

typedef __attribute__((ext_vector_type(8)))  short short8v;
typedef __attribute__((ext_vector_type(16))) float f32x16;
typedef __attribute__((ext_vector_type(2)))  int   v2i;

union B8u { uint u[4]; short8v v; };

static __device__ inline uint cvtpk(float lo, float hi) {
    uint r;
    asm("v_cvt_pk_bf16_f32 %0, %1, %2" : "=v"(r) : "v"(lo), "v"(hi));
    return r;
}
static __device__ inline void lswap(uint a, uint b, uint& x, uint& y, int hi) {
#if __has_builtin(__builtin_amdgcn_permlane32_swap)
    v2i r = __builtin_amdgcn_permlane32_swap((int)a, (int)b, false, false);
    x = (uint)r.x;
    y = (uint)r.y;
#else
    uint bx = (uint)__shfl_xor((int)b, 32);
    uint ax = (uint)__shfl_xor((int)a, 32);
    x = hi ? bx : a;
    y = hi ? b : ax;
#endif
}
static __device__ inline float fexp2(float v) {
#if __has_builtin(__builtin_amdgcn_exp2f)
    return __builtin_amdgcn_exp2f(v);
#else
    return __expf(v * 0.6931471805599453f);
#endif
}
// C-frag (32x32 acc) -> two operand frags via verified lswap transform
static __device__ inline void xform(const f32x16& acc, int hi, short8v& F1, short8v& F2) {
    uint a0 = cvtpk(acc[0],  acc[1]),  a1 = cvtpk(acc[2],  acc[3]);
    uint b0 = cvtpk(acc[4],  acc[5]),  b1 = cvtpk(acc[6],  acc[7]);
    uint a2 = cvtpk(acc[8],  acc[9]),  a3 = cvtpk(acc[10], acc[11]);
    uint b2 = cvtpk(acc[12], acc[13]), b3 = cvtpk(acc[14], acc[15]);
    B8u f1, f2;
    lswap(a0, b0, f1.u[0], f1.u[2], hi);
    lswap(a1, b1, f1.u[1], f1.u[3], hi);
    lswap(a2, b2, f2.u[0], f2.u[2], hi);
    lswap(a3, b3, f2.u[1], f2.u[3], hi);
    F1 = f1.v; F2 = f2.v;
}

// -------- fused prep+GEMM, K-split x2: 1008 blocks, 2 waves per 32x32 tile --------
// q-blocks [0,576): nc = bid>>1, mb = (bid&1)*2 + tib
// k-blocks [576,720): nc = (bid-576)>>1, mb = ((bid-576)&1)*2 + tib
// v-blocks [720,1008): kc = (bid-720)>>2, cb = ((bid-720)&3)*2 + tib
#define GQ_B 576
#define GK_B (GQ_B + 144)    // 720
#define G_ALL (GK_B + 288)   // 1008

__global__ __launch_bounds__(256) void gemm_all(
    const float* __restrict__ x,
    const float* __restrict__ wq, const float* __restrict__ bq,
    const float* __restrict__ wk, const float* __restrict__ bk_,
    const float* __restrict__ wv,
    ushort* __restrict__ qpack, ushort* __restrict__ kpack, ushort* __restrict__ vpack)
{
    __shared__ ushort Bf[KSTEPS][64][8];   // 16 KB staged B-tile
    __shared__ float prt[2][64][17];       // 8.7 KB K-half partials (stride 17: conflict-free)
    const int tid = threadIdx.x, lane = tid & 63, wvi = tid >> 6;
    const int hi = lane >> 5;
    const int tib = wvi >> 1;              // tile within block: 0/1
    const int kh  = wvi & 1;               // K-half: 0 -> channels 0..127, 1 -> 128..255
    const int bid = blockIdx.x;

    // ---- stage B-frag tile into LDS (all 256 threads) ----
    {
        int c = tid & 31;
        int ko0 = (tid >> 5) * 4;
        if (bid < GQ_B) {
            int col = (bid >> 1) * 32 + c;
            #pragma unroll
            for (int u = 0; u < 4; ++u) {
                int ko = ko0 + u;
                const float* xp_ = x + (size_t)(8 * ko) * NQ + col;
                float f[8];
                #pragma unroll
                for (int j = 0; j < 8; ++j) f[j] = xp_[(size_t)j * NQ];
                uint4 w;
                w.x = cvtpk(f[0], f[1]); w.y = cvtpk(f[2], f[3]);
                w.z = cvtpk(f[4], f[5]); w.w = cvtpk(f[6], f[7]);
                *(uint4*)&Bf[ko >> 1][32 * (ko & 1) + c][0] = w;
            }
        } else {
            int kc = (bid < GK_B) ? ((bid - GQ_B) >> 1) : ((bid - GK_B) >> 2);
            int np = kc * 32 + c;
            int py = np / WD, px = np - py * WD;
            const float* base = x + (2 * py) * W_ + 2 * px;
            #pragma unroll
            for (int u = 0; u < 4; ++u) {
                int ko = ko0 + u;
                const float* xp_ = base + (size_t)(8 * ko) * NQ;
                float f[8];
                #pragma unroll
                for (int j = 0; j < 8; ++j) {
                    const float* p = xp_ + (size_t)j * NQ;
                    f[j] = fmaxf(fmaxf(p[0], p[1]), fmaxf(p[W_], p[W_ + 1]));
                }
                uint4 w;
                w.x = cvtpk(f[0], f[1]); w.y = cvtpk(f[2], f[3]);
                w.z = cvtpk(f[4], f[5]); w.w = cvtpk(f[6], f[7]);
                *(uint4*)&Bf[ko >> 1][32 * (ko & 1) + c][0] = w;
            }
        }
    }
    __syncthreads();

    // ---- compute: each wave does its K-half of one 32x32 tile (8 chained MFMAs) ----
    f32x16 acc;
    #pragma unroll
    for (int r = 0; r < 16; ++r) acc[r] = 0.0f;

    const float* Wsrc;
    if (bid < GQ_B) {
        int mb = (bid & 1) * 2 + tib;
        Wsrc = wq + (size_t)(mb * 32 + (lane & 31)) * C_IN + 8 * hi;
    } else if (bid < GK_B) {
        int mb = ((bid - GQ_B) & 1) * 2 + tib;
        Wsrc = wk + (size_t)(mb * 32 + (lane & 31)) * C_IN + 8 * hi;
    } else {
        int cb = ((bid - GK_B) & 3) * 2 + tib;
        Wsrc = wv + (size_t)(cb * 32 + (lane & 31)) * C_IN + 8 * hi;
    }

    #pragma unroll
    for (int ss = 0; ss < 8; ++ss) {
        int s = 8 * kh + ss;
        float4 wa = *(const float4*)(Wsrc + 16 * s);
        float4 wb = *(const float4*)(Wsrc + 16 * s + 4);
        B8u af;
        af.u[0] = cvtpk(wa.x, wa.y); af.u[1] = cvtpk(wa.z, wa.w);
        af.u[2] = cvtpk(wb.x, wb.y); af.u[3] = cvtpk(wb.z, wb.w);
        short8v b = *(const short8v*)&Bf[s][lane][0];
        if (bid < GK_B)
            acc = __builtin_amdgcn_mfma_f32_32x32x16_bf16(af.v, b, acc, 0, 0, 0);
        else  // v-path: pooled tile is A (rows = keys), weights are B
            acc = __builtin_amdgcn_mfma_f32_32x32x16_bf16(b, af.v, acc, 0, 0, 0);
    }

    // ---- combine K-halves through LDS; kh=0 wave finishes ----
    if (kh == 1) {
        float* pw = &prt[tib][lane][0];
        #pragma unroll
        for (int r = 0; r < 16; ++r) pw[r] = acc[r];
    }
    __syncthreads();
    if (kh == 0) {
        const float* pw = &prt[tib][lane][0];
        #pragma unroll
        for (int r = 0; r < 16; ++r) acc[r] += pw[r];

        short8v F1, F2;
        if (bid < GQ_B) {                       // (acc + bq) * QS
            int nc = bid >> 1, mb = (bid & 1) * 2 + tib;
            #pragma unroll
            for (int r = 0; r < 16; ++r)
                acc[r] = (acc[r] + bq[mb * 32 + (r & 3) + 8 * (r >> 2) + 4 * hi]) * QS;
            xform(acc, hi, F1, F2);
            *(short8v*)&qpack[((size_t)((2 * mb)     * NQC + nc) * 64 + lane) * 8] = F1;
            *(short8v*)&qpack[((size_t)((2 * mb + 1) * NQC + nc) * 64 + lane) * 8] = F2;
        } else if (bid < GK_B) {                // acc + bk
            int nc = (bid - GQ_B) >> 1, mb = ((bid - GQ_B) & 1) * 2 + tib;
            #pragma unroll
            for (int r = 0; r < 16; ++r)
                acc[r] += bk_[mb * 32 + (r & 3) + 8 * (r >> 2) + 4 * hi];
            xform(acc, hi, F1, F2);
            *(short8v*)&kpack[((size_t)((2 * mb)     * NKC + nc) * 64 + lane) * 8] = F1;
            *(short8v*)&kpack[((size_t)((2 * mb + 1) * NKC + nc) * 64 + lane) * 8] = F2;
        } else {                                // v: C^T[key][c], no bias
            int kc = (bid - GK_B) >> 2, cb = ((bid - GK_B) & 3) * 2 + tib;
            xform(acc, hi, F1, F2);
            *(short8v*)&vpack[((size_t)((cb * NKC + kc) * 2 + 0) * 64 + lane) * 8] = F1;
            *(short8v*)&vpack[((size_t)((cb * NKC + kc) * 2 + 1) * 64 + lane) * 8] = F2;
        }
    }
}

// ---------------- fused attention (R8-verified, unchanged) ----------------
#define CSTR 17

static __device__ inline void attn_step(short8v kc_, short8v qf, short8v v0c, short8v v1c,
                                        f32x16& o, float& rsA, float& rsB,
                                        const f32x16& zc, int hi) {
    f32x16 s = __builtin_amdgcn_mfma_f32_32x32x16_bf16(kc_, qf, zc, 0, 0, 0);
    // half 1: acc regs 0..7 (k rows 0..15) -> PV with v0
    {
        float e0 = fexp2(s[0]), e1 = fexp2(s[1]), e2 = fexp2(s[2]), e3 = fexp2(s[3]);
        float e4 = fexp2(s[4]), e5 = fexp2(s[5]), e6 = fexp2(s[6]), e7 = fexp2(s[7]);
        rsA += ((e0 + e1) + (e2 + e3)) + ((e4 + e5) + (e6 + e7));
        uint a0 = cvtpk(e0, e1), a1 = cvtpk(e2, e3);
        uint b0 = cvtpk(e4, e5), b1 = cvtpk(e6, e7);
        B8u B1;
        lswap(a0, b0, B1.u[0], B1.u[2], hi);
        lswap(a1, b1, B1.u[1], B1.u[3], hi);
        o = __builtin_amdgcn_mfma_f32_32x32x16_bf16(v0c, B1.v, o, 0, 0, 0);
    }
    // half 2: acc regs 8..15 (k rows 16..31) -> PV with v1
    {
        float e0 = fexp2(s[8]),  e1 = fexp2(s[9]),  e2 = fexp2(s[10]), e3 = fexp2(s[11]);
        float e4 = fexp2(s[12]), e5 = fexp2(s[13]), e6 = fexp2(s[14]), e7 = fexp2(s[15]);
        rsB += ((e0 + e1) + (e2 + e3)) + ((e4 + e5) + (e6 + e7));
        uint a0 = cvtpk(e0, e1), a1 = cvtpk(e2, e3);
        uint b0 = cvtpk(e4, e5), b1 = cvtpk(e6, e7);
        B8u B2;
        lswap(a0, b0, B2.u[0], B2.u[2], hi);
        lswap(a1, b1, B2.u[1], B2.u[3], hi);
        o = __builtin_amdgcn_mfma_f32_32x32x16_bf16(v1c, B2.v, o, 0, 0, 0);
    }
}

__global__ __launch_bounds__(256) void attn_kernel(const ushort* __restrict__ qpack,
                                                   const ushort* __restrict__ kpack,
                                                   const ushort* __restrict__ vpack,
                                                   const float* __restrict__ x,
                                                   float* __restrict__ out) {
    __shared__ float part[4][64][CSTR];    // 17.4 KB
    const int h = blockIdx.y, qc = blockIdx.x;
    const int tid = threadIdx.x, lane = tid & 63;
    const int kh = tid >> 6;               // key quarter 0..3
    const int q31 = lane & 31, hi = lane >> 5;

    short8v qf = *(const short8v*)&qpack[((size_t)(h * NQC + qc) * 64 + lane) * 8];

    const char* kp = (const char*)(kpack + ((size_t)(h * NKC + kh * KQRT) * 64 + lane) * 8);
    const char* vp = (const char*)(vpack + ((size_t)(h * NKC + kh * KQRT) * 2 * 64 + lane) * 8);

    short8v kf  = *(const short8v*)kp;
    short8v v0f = *(const short8v*)vp;
    short8v v1f = *(const short8v*)(vp + 1024);

    f32x16 o, zc;
    #pragma unroll
    for (int r = 0; r < 16; ++r) { o[r] = 0.0f; zc[r] = 0.0f; }
    float rsA = 0.0f, rsB = 0.0f;

    #pragma unroll 2
    for (int c = 0; c < KQRT - 1; ++c) {
        kp += 1024; vp += 2048;
        short8v kn  = *(const short8v*)kp;
        short8v v0n = *(const short8v*)vp;
        short8v v1n = *(const short8v*)(vp + 1024);
        attn_step(kf, qf, v0f, v1f, o, rsA, rsB, zc, hi);
        kf = kn; v0f = v0n; v1f = v1n;
    }
    attn_step(kf, qf, v0f, v1f, o, rsA, rsB, zc, hi);   // peeled last chunk

    float rs = rsA + rsB;
    rs += __shfl_xor(rs, 32);

    {
        float* pw = &part[kh][lane][0];
        #pragma unroll
        for (int r = 0; r < 16; ++r) pw[r] = o[r];
        pw[16] = rs;
    }
    __syncthreads();

    float rsAll = part[0][lane][16] + part[1][lane][16]
                + part[2][lane][16] + part[3][lane][16];
    float inv = 1.0f / rsAll;
    int q = qc * 32 + q31;
    #pragma unroll
    for (int i = 0; i < 4; ++i) {
        int r = 4 * kh + i;
        float val = part[0][lane][r] + part[1][lane][r]
                  + part[2][lane][r] + part[3][lane][r];
        int dv = i + 8 * kh + 4 * hi;          // == crow(r,hi)
        size_t i0 = (size_t)(h * DV + dv) * NQ + q;
        out[i0] = val * inv + x[i0];
    }
}

// ---------------- launcher ----------------
extern "C" void kernel_launch(void* const* d_in, const int* in_sizes, int n_in,
                              void* d_out, int out_size, void* d_ws, size_t ws_size,
                              hipStream_t stream) {
    const float* x  = (const float*)d_in[0];
    const float* wq = (const float*)d_in[1];
    const float* bq = (const float*)d_in[2];
    const float* wk = (const float*)d_in[3];
    const float* bk = (const float*)d_in[4];
    const float* wv = (const float*)d_in[5];
    float* out = (float*)d_out;

    ushort* p = (ushort*)d_ws;
    ushort* qpack = p;  p += (size_t)NH * NQC * 64 * 8;      // 2.36 MB
    ushort* kpack = p;  p += (size_t)NH * NKC * 64 * 8;      // 0.59 MB
    ushort* vpack = p;  p += (size_t)NH * NKC * 2 * 64 * 8;  // 1.18 MB

    gemm_all<<<G_ALL, 256, 0, stream>>>(x, wq, bq, wk, bk, wv, qpack, kpack, vpack);
    attn_kernel<<<dim3(NQC, NH), 256, 0, stream>>>(qpack, kpack, vpack, x, out);
}